// Round 7
// baseline (181.562 us; speedup 1.0000x reference)
//
#include <hip/hip_runtime.h>
#include <hip/hip_bf16.h>

#define NROW 8192
#define FIN  512
#define FOUT 64
#define NHEAD 4

constexpr float LOG2E = 1.44269504088896f;

typedef float f32x4 __attribute__((ext_vector_type(4)));
typedef __bf16 bf16x8 __attribute__((ext_vector_type(8)));

// ---------------------------------------------------------------------------
// K0: WT[hd][o][f] = bf16(W[hd][f][o])
// ---------------------------------------------------------------------------
__global__ __launch_bounds__(256) void wt_build(
    const float* __restrict__ W, __hip_bfloat16* __restrict__ WT)
{
  int t = blockIdx.x * 256 + threadIdx.x;       // 2048 threads = 4 heads x 512 f
  int hd = t >> 9, f = t & 511;
  const float* wp = W + (hd * FIN + f) * FOUT;
#pragma unroll 8
  for (int o = 0; o < FOUT; ++o)
    WT[(hd * FOUT + o) * FIN + f] = __float2bfloat16(wp[o]);
}

// ---------------------------------------------------------------------------
// K1: h = x*W via MFMA. Block = one head, 4 waves, 64 n-rows.
// WT head staged once in XOR-swizzled LDS; epilogue transposes hT through LDS
// for coalesced stores. (unchanged from R6 - verified)
// ---------------------------------------------------------------------------
__global__ __launch_bounds__(256) void gat_proj(
    const float* __restrict__ x, const __hip_bfloat16* __restrict__ WT,
    const float* __restrict__ a1, const float* __restrict__ a2,
    __hip_bfloat16* __restrict__ hT, float* __restrict__ f1,
    float* __restrict__ E2, float* __restrict__ D2)
{
  const int tid = threadIdx.x;
  const int wid = tid >> 6, lane = tid & 63;
  const int il = lane & 15, kg = lane >> 4;
  const int hd = blockIdx.x & 3;
  const int rg = blockIdx.x >> 2;
  const int n0 = rg * 64;

  __shared__ __align__(16) __hip_bfloat16 wt_lds[64 * 512];   // 64 KB
  __shared__ __align__(16) __hip_bfloat16 ht_tile[64 * 66];   // 8.25 KB

  {
    const int o = tid >> 2, q = tid & 3;
    const __hip_bfloat16* src = WT + (size_t)(hd * FOUT + o) * FIN;
#pragma unroll
    for (int k = 0; k < 16; ++k) {
      int u = q * 16 + k;
      bf16x8 vv = *(const bf16x8*)(src + u * 8);
      *(bf16x8*)(&wt_lds[o * 512 + (u ^ (o & 7)) * 8]) = vv;
    }
  }
  __syncthreads();

  const int n = n0 + wid * 16 + il;
  const float* xp = x + (size_t)n * FIN + kg * 8;

  f32x4 acc[4];
#pragma unroll
  for (int c = 0; c < 4; ++c) { f32x4 z = {0.f,0.f,0.f,0.f}; acc[c] = z; }

#pragma unroll 4
  for (int kk = 0; kk < FIN / 32; ++kk) {
    f32x4 xl = *(const f32x4*)(xp + kk * 32);
    f32x4 xh = *(const f32x4*)(xp + kk * 32 + 4);
    bf16x8 xb;
#pragma unroll
    for (int e = 0; e < 4; ++e) {
      xb[e]     = (__bf16)xl[e];
      xb[4 + e] = (__bf16)xh[e];
    }
#pragma unroll
    for (int c = 0; c < 4; ++c) {
      const int o = c * 16 + il;
      bf16x8 af = *(const bf16x8*)(
          &wt_lds[o * 512 + ((kk * 4 + kg) ^ (il & 7)) * 8]);
      acc[c] = __builtin_amdgcn_mfma_f32_16x16x32_bf16(af, xb, acc[c], 0, 0, 0);
    }
  }

  float p1 = 0.f, p2 = 0.f;
#pragma unroll
  for (int c = 0; c < 4; ++c) {
    f32x4 a1v = *(const f32x4*)(a1 + hd * FOUT + c * 16 + kg * 4);
    f32x4 a2v = *(const f32x4*)(a2 + hd * FOUT + c * 16 + kg * 4);
#pragma unroll
    for (int r = 0; r < 4; ++r) {
      p1 = fmaf(acc[c][r], a1v[r], p1);
      p2 = fmaf(acc[c][r], a2v[r], p2);
    }
  }
  p1 += __shfl_xor(p1, 16); p1 += __shfl_xor(p1, 32);
  p2 += __shfl_xor(p2, 16); p2 += __shfl_xor(p2, 32);
  if (kg == 0) {
    float f1c = p1 * LOG2E;
    float f2c = p2 * LOG2E;
    f1[hd * NROW + n] = f1c;
    E2[hd * NROW + n] = __builtin_amdgcn_exp2f(f2c);
    D2[hd * NROW + n] = __builtin_amdgcn_exp2f(0.2f * f2c);
  }

#pragma unroll
  for (int c = 0; c < 4; ++c)
#pragma unroll
    for (int r = 0; r < 4; ++r)
      ht_tile[(c * 16 + kg * 4 + r) * 66 + wid * 16 + il] =
          __float2bfloat16(acc[c][r]);
  __syncthreads();
  {
    const int o = tid >> 2, q = tid & 3;
    bf16x8 t0 = *(const bf16x8*)(&ht_tile[o * 66 + q * 16]);
    bf16x8 t1 = *(const bf16x8*)(&ht_tile[o * 66 + q * 16 + 8]);
    __hip_bfloat16* dst = hT + (size_t)(hd * FOUT + o) * NROW + n0 + q * 16;
    *(bf16x8*)(dst)     = t0;
    *(bf16x8*)(dst + 8) = t1;
  }
}

// ---------------------------------------------------------------------------
// K3 (fused): attention partials with IN-KERNEL adj->mask (no mask_build).
// Block = 64 rows x 2048-m chunk x ALL 4 heads (wave = head): adj element
// read exactly once. Wave wid also packs adj rows [wid*16, wid*16+16) via
// ballot into a double-buffered LDS mask tile (1 barrier/iter).
// E2/D2 chunk tables (all heads) in LDS; hT frags direct-global with
// register prefetch (statically indexed 2-step pipeline).
// Epilogue: acc transposed through LDS -> column-major part, coalesced.
// ---------------------------------------------------------------------------
__global__ __launch_bounds__(256, 2) void gat_attn(
    const int* __restrict__ adj, const __hip_bfloat16* __restrict__ hTg,
    const float* __restrict__ f1, const float* __restrict__ E2g,
    const float* __restrict__ D2g, float* __restrict__ part)
{
  constexpr int S = 4;
  constexpr int MCH = NROW / S;       // 2048
  constexpr int ITERS = MCH / 64;     // 32
  const int tid = threadIdx.x;
  const int wid = tid >> 6, lane = tid & 63;   // wid = head
  const int il = lane & 15, kg = lane >> 4;

  const int nwg = S * 128;                       // 512
  const int bid = (blockIdx.x & 7) * (nwg >> 3) + (blockIdx.x >> 3);
  const int rg = bid & 127, mc = bid >> 7;
  const int n0 = rg * 64;
  const int mbase = mc * MCH;

  __shared__ __align__(16) float tbl[2 * NHEAD * MCH];   // 64 KB; reused as ep
  __shared__ unsigned int lmask[2][64][2];               // 1 KB
  __shared__ float dnl[NHEAD][64];                       // 1 KB

  float* tE = tbl;
  float* tD = tbl + NHEAD * MCH;

  // stage E2/D2 tables for all heads (f32x4, L2-hot)
#pragma unroll
  for (int q = 0; q < NHEAD * MCH / 1024; ++q) {
    int idx = (q * 256 + tid) * 4;
    int hd = idx / MCH, m = idx & (MCH - 1);
    *(f32x4*)(tE + idx) = *(const f32x4*)(E2g + hd * NROW + mbase + m);
    *(f32x4*)(tD + idx) = *(const f32x4*)(D2g + hd * NROW + mbase + m);
  }

  // per-lane row constants for this wave's head
  float E1[4], D1[4], iE1[4];
#pragma unroll
  for (int ng = 0; ng < 4; ++ng) {
    float fv = f1[wid * NROW + n0 + ng * 16 + il];
    E1[ng]  = __builtin_amdgcn_exp2f(fv);
    D1[ng]  = __builtin_amdgcn_exp2f(0.2f * fv);
    iE1[ng] = __builtin_amdgcn_exp2f(-fv);
  }

  // adj pack prologue: masks for it=0, then load av for it=1
  const int* ap = adj + (size_t)(n0 + wid * 16) * NROW + mbase;
  int av[16];
#pragma unroll
  for (int r = 0; r < 16; ++r) av[r] = ap[(size_t)r * NROW + lane];
#pragma unroll
  for (int r = 0; r < 16; ++r) {
    unsigned long long b = __ballot(av[r] != 0);
    if (lane == 0) {
      lmask[0][wid * 16 + r][0] = (unsigned)b;
      lmask[0][wid * 16 + r][1] = (unsigned)(b >> 32);
    }
  }
#pragma unroll
  for (int r = 0; r < 16; ++r) av[r] = ap[(size_t)r * NROW + 64 + lane];

  // hT fragment prologue (it=0)
  const __hip_bfloat16* hbase = hTg + (size_t)(wid * FOUT) * NROW + mbase;
  bf16x8 afrA[8], afrB[8];
#pragma unroll
  for (int ks = 0; ks < 2; ++ks)
#pragma unroll
    for (int c = 0; c < 4; ++c)
      afrA[ks * 4 + c] =
          *(const bf16x8*)(hbase + (c * 16 + il) * NROW + ks * 32 + kg * 8);

  f32x4 acc[4][4], accD[4];
#pragma unroll
  for (int ng = 0; ng < 4; ++ng) {
    f32x4 z = {0.f, 0.f, 0.f, 0.f};
#pragma unroll
    for (int c = 0; c < 4; ++c) acc[ng][c] = z;
    accD[ng] = z;
  }

  bf16x8 ones;
#pragma unroll
  for (int e = 0; e < 8; ++e) ones[e] = (__bf16)1.0f;

  __syncthreads();

  auto body = [&](int it, bf16x8 (&afrC)[8], bf16x8 (&afrN)[8], int cur) {
    const int nxt = cur ^ 1;
    // ballots for it+1 (av holds adj of it+1)
    if (it + 1 < ITERS) {
#pragma unroll
      for (int r = 0; r < 16; ++r) {
        unsigned long long b = __ballot(av[r] != 0);
        if (lane == 0) {
          lmask[nxt][wid * 16 + r][0] = (unsigned)b;
          lmask[nxt][wid * 16 + r][1] = (unsigned)(b >> 32);
        }
      }
    }
    // av <- it+2
    if (it + 2 < ITERS) {
#pragma unroll
      for (int r = 0; r < 16; ++r)
        av[r] = ap[(size_t)r * NROW + (it + 2) * 64 + lane];
    }
    // afr <- it+1
    if (it + 1 < ITERS) {
#pragma unroll
      for (int ks = 0; ks < 2; ++ks)
#pragma unroll
        for (int c = 0; c < 4; ++c)
          afrN[ks * 4 + c] = *(const bf16x8*)(
              hbase + (c * 16 + il) * NROW + (it + 1) * 64 + ks * 32 + kg * 8);
    }
    // compute iteration `it`
#pragma unroll
    for (int ks = 0; ks < 2; ++ks) {
      const int mof = it * 64 + ks * 32 + kg * 8;
      f32x4 e2l = *(const f32x4*)(tE + wid * MCH + mof);
      f32x4 e2h = *(const f32x4*)(tE + wid * MCH + mof + 4);
      f32x4 d2l = *(const f32x4*)(tD + wid * MCH + mof);
      f32x4 d2h = *(const f32x4*)(tD + wid * MCH + mof + 4);
#pragma unroll
      for (int ng = 0; ng < 4; ++ng) {
        unsigned mvs = lmask[cur][ng * 16 + il][ks] >> (kg * 8);
        float p[8];
#pragma unroll
        for (int e = 0; e < 8; ++e) {
          float E2v = (e < 4) ? e2l[e] : e2h[e - 4];
          float D2v = (e < 4) ? d2l[e] : d2h[e - 4];
          bool neg = E2v < iE1[ng];                   // s < 0
          float c2 = neg ? D2v : E2v;
          float c1 = neg ? D1[ng] : E1[ng];
          float q = c1 * c2;
          int msk = ((int)(mvs << (31 - e))) >> 31;   // bit e -> 0 / -1
          p[e] = __uint_as_float(__float_as_uint(q) & (unsigned)msk);
        }
        bf16x8 pb;
#pragma unroll
        for (int e = 0; e < 8; ++e) pb[e] = (__bf16)p[e];
#pragma unroll
        for (int c = 0; c < 4; ++c)
          acc[ng][c] = __builtin_amdgcn_mfma_f32_16x16x32_bf16(
              afrC[ks * 4 + c], pb, acc[ng][c], 0, 0, 0);
        accD[ng] = __builtin_amdgcn_mfma_f32_16x16x32_bf16(
            ones, pb, accD[ng], 0, 0, 0);
      }
    }
    __syncthreads();
  };

  for (int it = 0; it < ITERS; it += 2) {
    body(it,     afrA, afrB, 0);
    body(it + 1, afrB, afrA, 1);
  }

  // ---- epilogue: transpose acc through LDS (reuse tbl), coalesced stores
  // (main-loop barrier already separates last table read from this reuse)
  float* ep = tbl;                         // [NHEAD][64 col][64 n] = 64 KB
#pragma unroll
  for (int ng = 0; ng < 4; ++ng) {
#pragma unroll
    for (int c = 0; c < 4; ++c)
#pragma unroll
      for (int r = 0; r < 4; ++r)
        ep[(wid * 64 + c * 16 + kg * 4 + r) * 64 + ng * 16 + il] =
            acc[ng][c][r];
    if (kg == 0) dnl[wid][ng * 16 + il] = accD[ng][0];
  }
  __syncthreads();

  float* pp = part + ((size_t)(mc * NHEAD + wid) * 65) * NROW + n0 + lane;
#pragma unroll
  for (int col = 0; col < 64; ++col)
    pp[(size_t)col * NROW] = ep[(wid * 64 + col) * 64 + lane];
  pp[(size_t)64 * NROW] = dnl[wid][lane];
}

// ---------------------------------------------------------------------------
// K4: combine 4 partial slices (column-major layout), divide, sigmoid, store.
// Block = (64 n) x (1 head); thread = (n_local, o-quarter).
// ---------------------------------------------------------------------------
__global__ __launch_bounds__(256) void gat_comb(
    const float* __restrict__ part, float* __restrict__ out)
{
  constexpr int S = 4;
  const int tid = threadIdx.x;
  const int hd = blockIdx.x & 3, nc = blockIdx.x >> 2;
  const int nl = tid >> 2, oq = tid & 3;
  const int n = nc * 64 + nl;

  float num[16];
#pragma unroll
  for (int c = 0; c < 16; ++c) num[c] = 0.f;
  float den = 0.f;

#pragma unroll
  for (int s = 0; s < S; ++s) {
    const float* pb = part + ((size_t)(s * NHEAD + hd) * 65) * NROW + n;
#pragma unroll
    for (int c = 0; c < 16; ++c)
      num[c] += pb[(size_t)(oq * 16 + c) * NROW];
    den += pb[(size_t)64 * NROW];
  }

  float invL = 1.0f / den;
  float* op = out + (size_t)n * (NHEAD * FOUT) + hd * FOUT + oq * 16;
#pragma unroll
  for (int g = 0; g < 4; ++g) {
    f32x4 r;
#pragma unroll
    for (int j = 0; j < 4; ++j)
      r[j] = 1.0f /
             (1.0f + __builtin_amdgcn_exp2f(-num[g * 4 + j] * invL * LOG2E));
    *(f32x4*)(op + g * 4) = r;
  }
}

extern "C" void kernel_launch(void* const* d_in, const int* in_sizes, int n_in,
                              void* d_out, int out_size, void* d_ws, size_t ws_size,
                              hipStream_t stream) {
  const float* x   = (const float*)d_in[0];
  const int*   adj = (const int*)d_in[1];
  const float* W   = (const float*)d_in[2];
  const float* a1  = (const float*)d_in[3];
  const float* a2  = (const float*)d_in[4];
  float* out = (float*)d_out;

  char* ws = (char*)d_ws;
  const size_t WT_OFF = 0;
  const size_t HT_OFF = WT_OFF + (size_t)NHEAD * FOUT * FIN * 2;     // 256 KB
  const size_t F1_OFF = HT_OFF + (size_t)NHEAD * FOUT * NROW * 2;    // 4 MB
  const size_t E2_OFF = F1_OFF + (size_t)NHEAD * NROW * 4;
  const size_t D2_OFF = E2_OFF + (size_t)NHEAD * NROW * 4;
  const size_t PT_OFF = D2_OFF + (size_t)NHEAD * NROW * 4;
  // part: [S=4][NHEAD][65][NROW] f32 = 34.1 MB; total ~38.8 MB (< ws)

  __hip_bfloat16* WT = (__hip_bfloat16*)(ws + WT_OFF);
  __hip_bfloat16* hT = (__hip_bfloat16*)(ws + HT_OFF);
  float* f1 = (float*)(ws + F1_OFF);
  float* E2 = (float*)(ws + E2_OFF);
  float* D2 = (float*)(ws + D2_OFF);
  float* part = (float*)(ws + PT_OFF);

  wt_build<<<8, 256, 0, stream>>>(W, WT);
  gat_proj<<<NHEAD * (NROW / 64), 256, 0, stream>>>(x, WT, a1, a2, hT, f1, E2, D2);
  gat_attn<<<512, 256, 0, stream>>>(adj, hT, f1, E2, D2, part);
  gat_comb<<<(NROW / 64) * NHEAD, 256, 0, stream>>>(part, out);
}